// Round 7
// baseline (355.762 us; speedup 1.0000x reference)
//
#include <hip/hip_runtime.h>
#include <hip/hip_bf16.h>

// WaveNet dilated conv stack, MI355X gfx950. Round 7:
//  - uniform per-layer kernel, NO conv LDS staging: MFMA B-fragments loaded
//    directly from the bf16 [T][C] plane (L2/L3 absorb the 3-tap re-reads)
//  - only 16KB LDS (1x1 staging) + ONE barrier per layer
//  - 256 threads, <=128 VGPR -> grid 1024 = one co-resident generation
//  - input transposed fp32 [C][T] -> bf16 [T][C] once by a tiny kernel

#define CH 64
#define TLEN 16384
#define NB 8
#define BN 128
#define NLAYER 10

typedef __attribute__((ext_vector_type(4))) float f32x4;
typedef __attribute__((ext_vector_type(8))) short s16x8;
typedef __attribute__((ext_vector_type(4))) unsigned short u16x4;

__device__ __forceinline__ unsigned short f2bf(float f) {
    union { float f; unsigned u; } v; v.f = f;
    unsigned r = v.u + 0x7fffu + ((v.u >> 16) & 1u);  // RNE
    return (unsigned short)(r >> 16);
}
__device__ __forceinline__ float bf2f(unsigned short u) {
    union { unsigned u; float f; } v; v.u = ((unsigned)u) << 16;
    return v.f;
}

#define NCONV (NLAYER * 4 * 2 * 6 * 64 * 8)   // 245760 bf16: 10x 128x192 A-frags
#define NOUT  (NLAYER * 4 * 2 * 64 * 8)       // 40960  bf16: 10x 64x64 A-frags

__global__ void pack_weights(const float* __restrict__ wconv,
                             const float* __restrict__ wout,
                             unsigned short* __restrict__ wcpk,
                             unsigned short* __restrict__ wopk)
{
    int idx = blockIdx.x * 256 + threadIdx.x;
    if (idx < NCONV) {
        int j = idx & 7, t = idx >> 3;
        int lane = t & 63; t >>= 6;
        int ks = t % 6;   t /= 6;
        int m  = t & 1;   t >>= 1;
        int wv = t & 3;   int l = t >> 2;
        int o  = (m * 4 + wv) * 16 + (lane & 15);
        int ck = ks * 32 + (lane >> 4) * 8 + j;
        int kk = ck >> 6, c = ck & 63;
        wcpk[idx] = f2bf(wconv[(((size_t)l * 128 + o) * CH + c) * 3 + (2 - kk)]);
    } else if (idx < NCONV + NOUT) {
        int id = idx - NCONV;
        int j = id & 7, t = id >> 3;
        int lane = t & 63; t >>= 6;
        int ks = t & 1;    t >>= 1;
        int wv = t & 3;    int l = t >> 2;
        int o  = wv * 16 + (lane & 15);
        int c  = ks * 32 + (lane >> 4) * 8 + j;
        wopk[id] = f2bf(wout[((size_t)l * CH + o) * CH + c]);
    }
}

// fp32 [B][C][T] -> bf16 [B][T][C] (64x64 LDS tile transpose)
__global__ __launch_bounds__(256)
void transpose_in(const float* __restrict__ x, unsigned short* __restrict__ plane)
{
    __shared__ unsigned short tile[64][65];
    const int tid = threadIdx.x;
    const int b = blockIdx.y, t0 = blockIdx.x * 64;
    const size_t xbase = (size_t)b * CH * TLEN;
    #pragma unroll
    for (int i = 0; i < 16; ++i) {
        const int c = i * 4 + (tid >> 6);
        const int t = tid & 63;
        tile[t][c] = f2bf(x[xbase + (size_t)c * TLEN + t0 + t]);
    }
    __syncthreads();
    #pragma unroll
    for (int i = 0; i < 16; ++i) {
        const int t = i * 4 + (tid >> 6);
        const int c = tid & 63;
        plane[xbase + (size_t)(t0 + t) * CH + c] = tile[t][c];
    }
}

// ---- uniform layer body -------------------------------------------------
template<bool LAST, bool GUARD>
__device__ __forceinline__ void tail_body(
    const unsigned short* __restrict__ xb,   // xin + xbase (bf16 [T][C])
    void* __restrict__ xout_, float* __restrict__ skip,
    unsigned short* __restrict__ as_,
    const s16x8* w0, const s16x8* w1, const s16x8* wa2,
    const float* bt, const float* bs, const float* bo,
    size_t xbase, int t0, int wv, int hrow, int kgrp, int dil)
{
    #pragma unroll
    for (int nt = 0; nt < 8; ++nt) {
        f32x4 aT = (f32x4){0.f, 0.f, 0.f, 0.f};
        f32x4 aS = (f32x4){0.f, 0.f, 0.f, 0.f};
        #pragma unroll
        for (int ks = 0; ks < 6; ++ks) {
            const int kb = ks * 4 + kgrp;
            const int kk = kb >> 3, c8i = kb & 7;
            const int t = t0 + nt * 16 + hrow - kk * dil;
            s16x8 bf;
            if (GUARD) {
                bf = (s16x8){0, 0, 0, 0, 0, 0, 0, 0};
                if (t >= 0)
                    bf = *reinterpret_cast<const s16x8*>(xb + (size_t)t * CH + c8i * 8);
            } else {
                bf = *reinterpret_cast<const s16x8*>(xb + (size_t)t * CH + c8i * 8);
            }
            aT = __builtin_amdgcn_mfma_f32_16x16x32_bf16(w0[ks], bf, aT, 0, 0, 0);
            aS = __builtin_amdgcn_mfma_f32_16x16x32_bf16(w1[ks], bf, aS, 0, 0, 0);
        }
        // gated activation; C/D: col n = lane&15, row = (lane>>4)*4 + r
        const int n = nt * 16 + hrow;
        #pragma unroll
        for (int r = 0; r < 4; ++r) {
            const float yt = aT[r] + bt[r];
            const float ys = aS[r] + bs[r];
            const float th = 2.f * __builtin_amdgcn_rcpf(1.f + __expf(-2.f * yt)) - 1.f;
            const float sg = __builtin_amdgcn_rcpf(1.f + __expf(-ys));
            const float av = th * sg;
            const int c = wv * 16 + kgrp * 4 + r;
            skip[xbase + (size_t)c * TLEN + t0 + n] = av;
            if (LAST) {
                const float res = bf2f(xb[(size_t)(t0 + n) * CH + c]);
                ((float*)xout_)[xbase + (size_t)c * TLEN + t0 + n] = av + res;
            } else {
                as_[(size_t)((c >> 3) * BN + n) * 8 + (c & 7)] = f2bf(av);
            }
        }
    }

    if (LAST) return;

    __syncthreads();

    // 1x1: out = Wout * a + bias + residual(global), stored bf16 [T][C]
    const int o0 = wv * 16 + kgrp * 4;
    unsigned short* xout = (unsigned short*)xout_;
    #pragma unroll
    for (int nt = 0; nt < 8; ++nt) {
        const int n = nt * 16 + hrow;
        f32x4 acc = (f32x4){0.f, 0.f, 0.f, 0.f};
        #pragma unroll
        for (int ks = 0; ks < 2; ++ks) {
            const s16x8 bf = *reinterpret_cast<const s16x8*>(
                &as_[(size_t)((ks * 4 + kgrp) * BN + n) * 8]);
            acc = __builtin_amdgcn_mfma_f32_16x16x32_bf16(wa2[ks], bf, acc, 0, 0, 0);
        }
        const u16x4 rv = *reinterpret_cast<const u16x4*>(xb + (size_t)(t0 + n) * CH + o0);
        u16x4 ov;
        #pragma unroll
        for (int r = 0; r < 4; ++r) ov[r] = f2bf(acc[r] + bo[r] + bf2f(rv[r]));
        *reinterpret_cast<u16x4*>(&xout[xbase + (size_t)(t0 + n) * CH + o0]) = ov;
    }
}

template<bool LAST>
__global__ __launch_bounds__(256, 4)
void wavenet_tail(const unsigned short* __restrict__ xin, void* __restrict__ xout_,
                  float* __restrict__ skip,
                  const unsigned short* __restrict__ wcpk,
                  const unsigned short* __restrict__ wopk,
                  const float* __restrict__ bconv, const float* __restrict__ bout,
                  int layer, int dil)
{
    __shared__ __align__(16) unsigned short as_[8 * BN * 8];   // 16 KB

    const int tid  = threadIdx.x;
    const int lane = tid & 63;
    const int wv   = tid >> 6;
    const int hrow = lane & 15;
    const int kgrp = lane >> 4;
    const int b  = blockIdx.y;
    const int t0 = blockIdx.x * BN;
    const size_t xbase = (size_t)b * CH * TLEN;
    const unsigned short* xb = xin + xbase;

    // conv A-fragments (packed, 16B vector loads)
    s16x8 w0[6], w1[6];
    {
        const unsigned short* basew = wcpk + ((size_t)(layer * 4 + wv) * 768 + lane) * 8;
        #pragma unroll
        for (int ks = 0; ks < 6; ++ks) {
            w0[ks] = *reinterpret_cast<const s16x8*>(basew + (size_t)ks * 512);
            w1[ks] = *reinterpret_cast<const s16x8*>(basew + (size_t)(6 + ks) * 512);
        }
    }
    s16x8 wa2[2];
    {
        const unsigned short* b2 = wopk + ((size_t)(layer * 4 + wv) * 128 + lane) * 8;
        wa2[0] = *reinterpret_cast<const s16x8*>(b2);
        wa2[1] = *reinterpret_cast<const s16x8*>(b2 + 512);
    }
    const float* Bc = bconv + (size_t)layer * 128;
    const float* Bo = bout + (size_t)layer * CH;
    float bt[4], bs[4], bo[4];
    #pragma unroll
    for (int r = 0; r < 4; ++r) {
        bt[r] = Bc[wv * 16 + kgrp * 4 + r];
        bs[r] = Bc[64 + wv * 16 + kgrp * 4 + r];
        bo[r] = Bo[wv * 16 + kgrp * 4 + r];
    }

    if (t0 >= 2 * dil)
        tail_body<LAST, false>(xb, xout_, skip, as_, w0, w1, wa2, bt, bs, bo,
                               xbase, t0, wv, hrow, kgrp, dil);
    else
        tail_body<LAST, true>(xb, xout_, skip, as_, w0, w1, wa2, bt, bs, bo,
                              xbase, t0, wv, hrow, kgrp, dil);
}

extern "C" void kernel_launch(void* const* d_in, const int* in_sizes, int n_in,
                              void* d_out, int out_size, void* d_ws, size_t ws_size,
                              hipStream_t stream)
{
    const float* x  = (const float*)d_in[0];
    const float* wc = (const float*)d_in[1];
    const float* bc = (const float*)d_in[2];
    const float* wo = (const float*)d_in[3];
    const float* bo = (const float*)d_in[4];
    float* out = (float*)d_out;
    const size_t planeF = (size_t)NB * CH * TLEN;   // elements per plane

    unsigned short* P0 = (unsigned short*)d_ws;
    unsigned short* P1 = P0 + planeF;
    unsigned short* wcpk = P1 + planeF;
    unsigned short* wopk = wcpk + NCONV;

    pack_weights<<<(NCONV + NOUT) / 256, 256, 0, stream>>>(wc, wo, wcpk, wopk);
    transpose_in<<<dim3(TLEN / 64, NB), 256, 0, stream>>>(x, P0);

    dim3 grid(TLEN / BN, NB), block(256);
    for (int i = 0; i < NLAYER; ++i) {
        unsigned short* xi = (i & 1) ? P1 : P0;
        unsigned short* xo = (i & 1) ? P0 : P1;
        float* skip = out + (size_t)(1 + i) * planeF;
        if (i < NLAYER - 1)
            wavenet_tail<false><<<grid, block, 0, stream>>>(
                xi, xo, skip, wcpk, wopk, bc, bo, i, 1 << i);
        else
            wavenet_tail<true><<<grid, block, 0, stream>>>(
                xi, out, skip, wcpk, wopk, bc, bo, i, 1 << i);
    }
}